// Round 8
// baseline (198.129 us; speedup 1.0000x reference)
//
#include <hip/hip_runtime.h>
#include <math.h>

// Problem constants (match reference)
#define NROWS 65536          // B*S = 16*4096
#define CIN   768
#define QCOUNT 524288.0      // NROWS * DDIM
#define RPW   4              // rows per wave
#define NBLK  (NROWS / (4 * RPW))   // 4096 blocks of 4 waves

// Fused temporal-phase kernel (R7 post-mortem): per wave,
//   phase A: compress+gumbel-argmax all RPW rows -> 4 packed u32 codes (regs)
//   phase B: expand those rows from the packed codes.
// Phase A state (f64 butterfly, z bufs) and phase B state (We/be accums)
// are never live simultaneously -> peak VGPR ~= phase A alone, unlike the
// R5 interleaved mono (148 VGPR). Cross-wave, phase B's HBM writes overlap
// phase A's DS-pipe work — the two-pass dispatch serialized them.
// Decision path byte-identical to the verified absmax-0.0 kernels.

// Distributing butterfly: reduce 8 per-lane f64 partials across 64 lanes,
// delivering zc[d] to lanes with (lane&7)==d. Fixed order, static selects.
#define REDUCE_TO_MINE(da, out)                                            \
    {                                                                      \
        double k0 = b0 ? da[1] : da[0], s0 = b0 ? da[0] : da[1];           \
        double k1 = b0 ? da[3] : da[2], s1 = b0 ? da[2] : da[3];           \
        double k2 = b0 ? da[5] : da[4], s2 = b0 ? da[4] : da[5];           \
        double k3 = b0 ? da[7] : da[6], s3 = b0 ? da[6] : da[7];           \
        k0 += __shfl_xor(s0, 1); k1 += __shfl_xor(s1, 1);                  \
        k2 += __shfl_xor(s2, 1); k3 += __shfl_xor(s3, 1);                  \
        double m0 = b1 ? k1 : k0, t0 = b1 ? k0 : k1;                       \
        double m1 = b1 ? k3 : k2, t1 = b1 ? k2 : k3;                       \
        m0 += __shfl_xor(t0, 2); m1 += __shfl_xor(t1, 2);                  \
        double r = b2 ? m1 : m0, tq = b2 ? m0 : m1;                        \
        r += __shfl_xor(tq, 4);                                            \
        r += __shfl_xor(r, 8);                                             \
        r += __shfl_xor(r, 16);                                            \
        r += __shfl_xor(r, 32);                                            \
        out = r;                                                           \
    }

// Load one row's z (3 coalesced float4) + u (coalesced permuted 256B)
#define LOADZ(B, row)                                                      \
    B##0 = z4[(size_t)(row) * 192 + lane];                                 \
    B##1 = z4[(size_t)(row) * 192 + lane + 64];                           \
    B##2 = z4[(size_t)(row) * 192 + lane + 128];                          \
    B##u = u[(size_t)(row) * 64 + dg * 8 + lev];

// compress: zc = z @ Wc (+bc). f32 FMA within 4-chunk, f64 chunk accum —
// EXACT same arithmetic order as the verified absmax-0.0 kernel; wA/wB
// sourced from XOR-swizzled LDS.
#define COMPRESS(B, ZCOUT)                                                 \
    {                                                                      \
        double da[8];                                                      \
        _Pragma("unroll") for (int d = 0; d < 8; ++d) da[d] = 0.0;         \
        _Pragma("unroll") for (int j = 0; j < 3; ++j) {                    \
            const float4 zv = (j == 0) ? B##0 : (j == 1) ? B##1 : B##2;    \
            const int fi = lane + 64 * j;                                  \
            const int sw = fi & 7;                                         \
            float f[8];                                                    \
            _Pragma("unroll") for (int d = 0; d < 8; ++d) f[d] = 0.f;      \
            _Pragma("unroll") for (int k = 0; k < 4; ++k) {                \
                const float a = (k==0)?zv.x:(k==1)?zv.y:(k==2)?zv.z:zv.w;  \
                const int a0 = 8 * fi + 2 * k;                             \
                const float4 wA = lds_w[a0 ^ sw];                          \
                const float4 wB = lds_w[(a0 + 1) ^ sw];                    \
                f[0]=fmaf(a,wA.x,f[0]); f[1]=fmaf(a,wA.y,f[1]);            \
                f[2]=fmaf(a,wA.z,f[2]); f[3]=fmaf(a,wA.w,f[3]);            \
                f[4]=fmaf(a,wB.x,f[4]); f[5]=fmaf(a,wB.y,f[5]);            \
                f[6]=fmaf(a,wB.z,f[6]); f[7]=fmaf(a,wB.w,f[7]);            \
            }                                                              \
            _Pragma("unroll") for (int d = 0; d < 8; ++d)                  \
                da[d] += (double)f[d];                                     \
        }                                                                  \
        REDUCE_TO_MINE(da, ZCOUT)                                         \
        ZCOUT += bc_mine;                                                  \
    }

// gumbel + argmax + qerr-accumulate + pack indices -> PKOUT (all lanes)
#define FIN_CODE(PKOUT, ZC, UVF)                                           \
    {                                                                      \
        const double uv = (double)(UVF) + 1e-10;                           \
        const double g  = -log(-log(uv));                                  \
        double n  = g - fabs(ZC - (double)cb_mine);   /* TAU = 1 */        \
        int    li = lev;                                                   \
        float  ci = cb_mine;                                               \
        _Pragma("unroll") for (int s = 8; s <= 32; s <<= 1) {              \
            const double on = __shfl_xor(n, s);                            \
            const int    ol = __shfl_xor(li, s);                           \
            const float  oc = __shfl_xor(ci, s);                           \
            const bool   t  = (on > n) || (on == n && ol < li);            \
            n = t ? on : n; li = t ? ol : li; ci = t ? oc : ci;            \
        }                                                                  \
        const double e = ZC - (double)ci;                                  \
        qa += e * e;                                                       \
        unsigned pk = (unsigned)li << (3 * dg);                            \
        pk += __shfl_xor(pk, 1);                                           \
        pk += __shfl_xor(pk, 2);                                           \
        pk += __shfl_xor(pk, 4);   /* full 24-bit pack in every lane */    \
        PKOUT = pk;                                                        \
    }

// expand one row from packed code PK (cb values via LDS broadcast —
// identical f32 values to the shuffled ci of the verified kernel)
#define EXPAND_ROW(row, PK)                                                \
    {                                                                      \
        float cd[8];                                                       \
        _Pragma("unroll") for (int d = 0; d < 8; ++d)                      \
            cd[d] = cbl[d * 8 + (((PK) >> (3 * d)) & 7)];                  \
        _Pragma("unroll") for (int j = 0; j < 3; ++j) {                    \
            const int fi = lane + 64 * j;                                  \
            float4 o = be4[fi];                                            \
            _Pragma("unroll") for (int d = 0; d < 8; ++d) {                \
                const float4 wv = We4[d * 192 + fi];                       \
                o.x = fmaf(cd[d], wv.x, o.x);                              \
                o.y = fmaf(cd[d], wv.y, o.y);                              \
                o.z = fmaf(cd[d], wv.z, o.z);                              \
                o.w = fmaf(cd[d], wv.w, o.w);                              \
            }                                                              \
            zq4[(size_t)(row) * 192 + fi] = o;                             \
        }                                                                  \
    }

template <int USE_BPART>
__global__ __launch_bounds__(256) void fsq_fused(
    const float* __restrict__ z, const float* __restrict__ u,
    const float* __restrict__ Wc, const float* __restrict__ bc,
    const float* __restrict__ We, const float* __restrict__ be,
    const float* __restrict__ cb, float* __restrict__ zq,
    double* __restrict__ bpart)
{
    __shared__ float4 lds_w[1536];   // Wc, XOR-swizzled
    __shared__ float  cbl[64];       // codebook copy for expand lookups
    __shared__ double wsum[4];

    const int lane = threadIdx.x & 63;
    const int wid  = threadIdx.x >> 6;
    const int dg   = lane & 7;
    const int lev  = lane >> 3;

    // ---- stage Wc (XOR-swizzled: idx ^ ((idx>>3)&7), involution) + cb ----
    {
        const float4* __restrict__ Wc4 = (const float4*)Wc;
        for (int t = threadIdx.x; t < 1536; t += 256)
            lds_w[t ^ ((t >> 3) & 7)] = Wc4[t];
        if (threadIdx.x < 64) cbl[threadIdx.x] = cb[threadIdx.x];
    }

    const float  cb_mine = cb[dg * 8 + lev];
    const double bc_mine = (double)bc[dg];
    const int b0 = lane & 1, b1 = (lane >> 1) & 1, b2 = (lane >> 2) & 1;

    const float4* __restrict__ z4  = (const float4*)z;
    const float4* __restrict__ We4 = (const float4*)We;
    const float4* __restrict__ be4 = (const float4*)be;
    float4* __restrict__ zq4 = (float4*)zq;

    const int wbase = (blockIdx.x * 4 + wid) * RPW;
    double qa = 0.0;

    __syncthreads();   // Wc image + cbl ready

    // ================= phase A: codes for all RPW rows =================
    float4 zA0, zA1, zA2, zB0, zB1, zB2;
    float  zAu, zBu, uvA, uvB;
    double zcA, zcB;
    unsigned pk0, pk1, pk2, pk3;

    LOADZ(zA, wbase + 0)
    LOADZ(zB, wbase + 1)
    COMPRESS(zA, zcA)
    uvA = zAu;
    LOADZ(zA, wbase + 2)              // prefetch row 2 under FIN+COMPRESS(B)
    FIN_CODE(pk0, zcA, uvA)
    COMPRESS(zB, zcB)
    uvB = zBu;
    LOADZ(zB, wbase + 3)              // prefetch row 3
    FIN_CODE(pk1, zcB, uvB)
    COMPRESS(zA, zcA)
    FIN_CODE(pk2, zcA, zAu)
    COMPRESS(zB, zcB)
    FIN_CODE(pk3, zcB, zBu)

    // ================= phase B: expand all RPW rows =================
    EXPAND_ROW(wbase + 0, pk0)
    EXPAND_ROW(wbase + 1, pk1)
    EXPAND_ROW(wbase + 2, pk2)
    EXPAND_ROW(wbase + 3, pk3)

    // ---- quantization error: dg-reduce once per wave ----
    qa += __shfl_xor(qa, 1);
    qa += __shfl_xor(qa, 2);
    qa += __shfl_xor(qa, 4);
    if (USE_BPART) {
        if (lane == 0) wsum[wid] = qa;
        __syncthreads();
        if (threadIdx.x == 0)
            bpart[blockIdx.x] = (wsum[0] + wsum[1]) + (wsum[2] + wsum[3]);
    } else {
        if (lane == 0) atomicAdd(bpart, qa);
    }
}

// Deterministic fixed-order reduction of NBLK partials -> mean -> out.
__global__ __launch_bounds__(256) void fsq_tail_bpart(
    const double* __restrict__ bpart, float* __restrict__ out)
{
    __shared__ double s[256];
    const int t = threadIdx.x;
    double a = 0.0;
    for (int i = 0; i < NBLK / 256; ++i)          // fixed order
        a += bpart[t * (NBLK / 256) + i];
    s[t] = a;
    __syncthreads();
    for (int w = 128; w > 0; w >>= 1) {
        if (t < w) s[t] += s[t + w];
        __syncthreads();
    }
    if (t == 0) out[0] = (float)(s[0] * (1.0 / QCOUNT));
}

__global__ void fsq_tail_atomic(const double* __restrict__ qacc, float* __restrict__ out)
{
    out[0] = (float)(qacc[0] * (1.0 / QCOUNT));
}

extern "C" void kernel_launch(void* const* d_in, const int* in_sizes, int n_in,
                              void* d_out, int out_size, void* d_ws, size_t ws_size,
                              hipStream_t stream)
{
    const float* z  = (const float*)d_in[0];
    const float* u  = (const float*)d_in[1];
    const float* Wc = (const float*)d_in[2];
    const float* bc = (const float*)d_in[3];
    const float* We = (const float*)d_in[4];
    const float* be = (const float*)d_in[5];
    const float* cb = (const float*)d_in[6];
    // d_in[7] = codebook_mask: all levels == 8 -> mask all true, unused.

    float*  zq    = (float*)d_out;
    double* bpart = (double*)d_ws;

    if (ws_size >= (size_t)NBLK * sizeof(double)) {
        // no memset needed: every block overwrites its own slot
        fsq_fused<1><<<dim3(NBLK), dim3(256), 0, stream>>>(z, u, Wc, bc, We, be, cb, zq, bpart);
        fsq_tail_bpart<<<dim3(1), dim3(256), 0, stream>>>(bpart, zq + (size_t)NROWS * CIN);
    } else {
        hipMemsetAsync(d_ws, 0, sizeof(double), stream);
        fsq_fused<0><<<dim3(NBLK), dim3(256), 0, stream>>>(z, u, Wc, bc, We, be, cb, zq, bpart);
        fsq_tail_atomic<<<dim3(1), dim3(1), 0, stream>>>(bpart, zq + (size_t)NROWS * CIN);
    }
}

// Round 9
// 145.229 us; speedup vs baseline: 1.3643x; 1.3643x over previous
//
#include <hip/hip_runtime.h>
#include <math.h>

// Problem constants (match reference)
#define NROWS 65536          // B*S = 16*4096
#define CIN   768
#define QCOUNT 524288.0      // NROWS * DDIM
#define RPW   4              // rows per wave, pass 1 (2 pairs)
#define NBLK  (NROWS / (4 * RPW))   // 4096 blocks of 4 waves (pass 1)
#define NBLK2 (NROWS / 16)          // 4096 blocks, expand: 4 rows/wave

// Two-pass structure (R7: 128.6us best; R8 fused regressed to 198 — dense
// COMPRESS scheduling 4x'd bank-conflict cycles and expand inherited low
// occupancy). This round: two-pass + COMPRESS2 (2 rows share each Wc LDS
// read -> DS traffic per row halved) + 4-row expand + tail folded into
// expand block 0. Decision path bit-identical to verified absmax-0.0.

// Distributing butterfly: reduce 8 per-lane f64 partials across 64 lanes,
// delivering zc[d] to lanes with (lane&7)==d. Fixed order, static selects.
#define REDUCE_TO_MINE(da, out)                                            \
    {                                                                      \
        double k0 = b0 ? da[1] : da[0], s0 = b0 ? da[0] : da[1];           \
        double k1 = b0 ? da[3] : da[2], s1 = b0 ? da[2] : da[3];           \
        double k2 = b0 ? da[5] : da[4], s2 = b0 ? da[4] : da[5];           \
        double k3 = b0 ? da[7] : da[6], s3 = b0 ? da[6] : da[7];           \
        k0 += __shfl_xor(s0, 1); k1 += __shfl_xor(s1, 1);                  \
        k2 += __shfl_xor(s2, 1); k3 += __shfl_xor(s3, 1);                  \
        double m0 = b1 ? k1 : k0, t0 = b1 ? k0 : k1;                       \
        double m1 = b1 ? k3 : k2, t1 = b1 ? k2 : k3;                       \
        m0 += __shfl_xor(t0, 2); m1 += __shfl_xor(t1, 2);                  \
        double r = b2 ? m1 : m0, tq = b2 ? m0 : m1;                        \
        r += __shfl_xor(tq, 4);                                            \
        r += __shfl_xor(r, 8);                                             \
        r += __shfl_xor(r, 16);                                            \
        r += __shfl_xor(r, 32);                                            \
        out = r;                                                           \
    }

// Load one row's z (3 coalesced float4) + u (coalesced permuted 256B)
#define LOADZ(B, row)                                                      \
    B##0 = z4[(size_t)(row) * 192 + lane];                                 \
    B##1 = z4[(size_t)(row) * 192 + lane + 64];                           \
    B##2 = z4[(size_t)(row) * 192 + lane + 128];                          \
    B##u = u[(size_t)(row) * 64 + dg * 8 + lev];

// compress TWO rows sharing each Wc LDS read. Per-row arithmetic is the
// EXACT order of the verified absmax-0.0 kernel (f32 FMA in 4-chunks,
// f64 chunk accumulation, same butterfly).
#define COMPRESS2(ZCA, ZCB)                                                \
    {                                                                      \
        double da0[8], da1[8];                                             \
        _Pragma("unroll") for (int d = 0; d < 8; ++d) { da0[d]=0.0; da1[d]=0.0; } \
        _Pragma("unroll") for (int j = 0; j < 3; ++j) {                    \
            const float4 zvA = (j == 0) ? zA0 : (j == 1) ? zA1 : zA2;      \
            const float4 zvB = (j == 0) ? zB0 : (j == 1) ? zB1 : zB2;      \
            const int fi = lane + 64 * j;                                  \
            const int sw = fi & 7;                                         \
            float fA[8], fB[8];                                            \
            _Pragma("unroll") for (int d = 0; d < 8; ++d) { fA[d]=0.f; fB[d]=0.f; } \
            _Pragma("unroll") for (int k = 0; k < 4; ++k) {                \
                const float aA = (k==0)?zvA.x:(k==1)?zvA.y:(k==2)?zvA.z:zvA.w; \
                const float aB = (k==0)?zvB.x:(k==1)?zvB.y:(k==2)?zvB.z:zvB.w; \
                const int a0 = 8 * fi + 2 * k;                             \
                const float4 wA = lds_w[a0 ^ sw];                          \
                const float4 wB = lds_w[(a0 + 1) ^ sw];                    \
                fA[0]=fmaf(aA,wA.x,fA[0]); fA[1]=fmaf(aA,wA.y,fA[1]);      \
                fA[2]=fmaf(aA,wA.z,fA[2]); fA[3]=fmaf(aA,wA.w,fA[3]);      \
                fA[4]=fmaf(aA,wB.x,fA[4]); fA[5]=fmaf(aA,wB.y,fA[5]);      \
                fA[6]=fmaf(aA,wB.z,fA[6]); fA[7]=fmaf(aA,wB.w,fA[7]);      \
                fB[0]=fmaf(aB,wA.x,fB[0]); fB[1]=fmaf(aB,wA.y,fB[1]);      \
                fB[2]=fmaf(aB,wA.z,fB[2]); fB[3]=fmaf(aB,wA.w,fB[3]);      \
                fB[4]=fmaf(aB,wB.x,fB[4]); fB[5]=fmaf(aB,wB.y,fB[5]);      \
                fB[6]=fmaf(aB,wB.z,fB[6]); fB[7]=fmaf(aB,wB.w,fB[7]);      \
            }                                                              \
            _Pragma("unroll") for (int d = 0; d < 8; ++d) {                \
                da0[d] += (double)fA[d];                                   \
                da1[d] += (double)fB[d];                                   \
            }                                                              \
        }                                                                  \
        REDUCE_TO_MINE(da0, ZCA)                                          \
        REDUCE_TO_MINE(da1, ZCB)                                          \
        ZCA += bc_mine;                                                    \
        ZCB += bc_mine;                                                    \
    }

// gumbel + argmax + qerr-accumulate + pack indices -> codes[row]
#define FIN_CODE(row, ZC, UVF)                                             \
    {                                                                      \
        const double uv = (double)(UVF) + 1e-10;                           \
        const double g  = -log(-log(uv));                                  \
        double n  = g - fabs(ZC - (double)cb_mine);   /* TAU = 1 */        \
        int    li = lev;                                                   \
        float  ci = cb_mine;                                               \
        _Pragma("unroll") for (int s = 8; s <= 32; s <<= 1) {              \
            const double on = __shfl_xor(n, s);                            \
            const int    ol = __shfl_xor(li, s);                           \
            const float  oc = __shfl_xor(ci, s);                           \
            const bool   t  = (on > n) || (on == n && ol < li);            \
            n = t ? on : n; li = t ? ol : li; ci = t ? oc : ci;            \
        }                                                                  \
        const double e = ZC - (double)ci;                                  \
        qa += e * e;                                                       \
        unsigned pk = (unsigned)li << (3 * dg);                            \
        pk += __shfl_xor(pk, 1);                                           \
        pk += __shfl_xor(pk, 2);                                           \
        pk += __shfl_xor(pk, 4);   /* full 24-bit pack in every lane */    \
        if (lane == 0) codes[row] = pk;                                    \
    }

// ---------------- Pass 1: compress + gumbel-argmax + qerr + codes ----------------
__global__ __launch_bounds__(256) void fsq_code(
    const float* __restrict__ z, const float* __restrict__ u,
    const float* __restrict__ Wc, const float* __restrict__ bc,
    const float* __restrict__ cb, unsigned* __restrict__ codes,
    double* __restrict__ bpart)
{
    __shared__ float4 lds_w[1536];   // Wc, XOR-swizzled
    __shared__ double wsum[4];

    const int lane = threadIdx.x & 63;
    const int wid  = threadIdx.x >> 6;
    const int dg   = lane & 7;
    const int lev  = lane >> 3;

    {
        const float4* __restrict__ Wc4 = (const float4*)Wc;
        for (int t = threadIdx.x; t < 1536; t += 256)
            lds_w[t ^ ((t >> 3) & 7)] = Wc4[t];
    }

    const float  cb_mine = cb[dg * 8 + lev];
    const double bc_mine = (double)bc[dg];
    const int b0 = lane & 1, b1 = (lane >> 1) & 1, b2 = (lane >> 2) & 1;

    const float4* __restrict__ z4 = (const float4*)z;

    const int wbase = (blockIdx.x * 4 + wid) * RPW;
    double qa = 0.0;

    __syncthreads();   // Wc image ready

    float4 zA0, zA1, zA2, zB0, zB1, zB2;
    float  zAu, zBu;
    double zcA, zcB;
#pragma unroll 1
    for (int itp = 0; itp < RPW / 2; ++itp) {
        const int r0 = wbase + 2 * itp;
        LOADZ(zA, r0)
        LOADZ(zB, r0 + 1)
        COMPRESS2(zcA, zcB)
        FIN_CODE(r0, zcA, zAu)
        FIN_CODE(r0 + 1, zcB, zBu)
    }

    // qerr block partial (deterministic)
    qa += __shfl_xor(qa, 1);
    qa += __shfl_xor(qa, 2);
    qa += __shfl_xor(qa, 4);
    if (lane == 0) wsum[wid] = qa;
    __syncthreads();
    if (threadIdx.x == 0)
        bpart[blockIdx.x] = (wsum[0] + wsum[1]) + (wsum[2] + wsum[3]);
}

// ---------------- Pass 2: expand codes -> z_q (streaming, 4 rows/wave) ----
// Block 0 additionally performs the deterministic qerr tail reduction
// (bpart is complete: pass 1 finished before this kernel starts).
__global__ __launch_bounds__(256) void fsq_expand(
    const unsigned* __restrict__ codes, const float* __restrict__ We,
    const float* __restrict__ be, const float* __restrict__ cb,
    const double* __restrict__ bpart, float* __restrict__ zq)
{
    __shared__ float cbl[64];
    __shared__ double s[256];

    if (blockIdx.x == 0) {
        const int t = threadIdx.x;
        double a = 0.0;
        for (int i = 0; i < NBLK / 256; ++i)      // fixed order
            a += bpart[t * (NBLK / 256) + i];
        s[t] = a;
        __syncthreads();
        for (int w = 128; w > 0; w >>= 1) {
            if (t < w) s[t] += s[t + w];
            __syncthreads();
        }
        if (t == 0) zq[(size_t)NROWS * CIN] = (float)(s[0] * (1.0 / QCOUNT));
    }

    if (threadIdx.x < 64) cbl[threadIdx.x] = cb[threadIdx.x];
    __syncthreads();

    const int lane = threadIdx.x & 63;
    const int wid  = threadIdx.x >> 6;
    const int gw   = blockIdx.x * 4 + wid;
    const int row0 = gw * 4;

    const unsigned c0 = codes[row0];     // wave-uniform broadcast loads
    const unsigned c1 = codes[row0 + 1];
    const unsigned c2 = codes[row0 + 2];
    const unsigned c3 = codes[row0 + 3];

    float cd0[8], cd1[8], cd2[8], cd3[8];
#pragma unroll
    for (int d = 0; d < 8; ++d) {
        cd0[d] = cbl[d * 8 + ((c0 >> (3 * d)) & 7)];   // LDS broadcast reads
        cd1[d] = cbl[d * 8 + ((c1 >> (3 * d)) & 7)];
        cd2[d] = cbl[d * 8 + ((c2 >> (3 * d)) & 7)];
        cd3[d] = cbl[d * 8 + ((c3 >> (3 * d)) & 7)];
    }

    const float4* __restrict__ We4 = (const float4*)We;
    const float4* __restrict__ be4 = (const float4*)be;
    float4* __restrict__ zq4 = (float4*)zq;
#pragma unroll
    for (int j = 0; j < 3; ++j) {
        const int fi = lane + 64 * j;
        const float4 bv = be4[fi];
        float4 o0 = bv, o1 = bv, o2 = bv, o3 = bv;
#pragma unroll
        for (int d = 0; d < 8; ++d) {
            const float4 wv = We4[d * 192 + fi];
            o0.x = fmaf(cd0[d], wv.x, o0.x); o0.y = fmaf(cd0[d], wv.y, o0.y);
            o0.z = fmaf(cd0[d], wv.z, o0.z); o0.w = fmaf(cd0[d], wv.w, o0.w);
            o1.x = fmaf(cd1[d], wv.x, o1.x); o1.y = fmaf(cd1[d], wv.y, o1.y);
            o1.z = fmaf(cd1[d], wv.z, o1.z); o1.w = fmaf(cd1[d], wv.w, o1.w);
            o2.x = fmaf(cd2[d], wv.x, o2.x); o2.y = fmaf(cd2[d], wv.y, o2.y);
            o2.z = fmaf(cd2[d], wv.z, o2.z); o2.w = fmaf(cd2[d], wv.w, o2.w);
            o3.x = fmaf(cd3[d], wv.x, o3.x); o3.y = fmaf(cd3[d], wv.y, o3.y);
            o3.z = fmaf(cd3[d], wv.z, o3.z); o3.w = fmaf(cd3[d], wv.w, o3.w);
        }
        zq4[(size_t)row0 * 192 + fi]       = o0;
        zq4[(size_t)(row0 + 1) * 192 + fi] = o1;
        zq4[(size_t)(row0 + 2) * 192 + fi] = o2;
        zq4[(size_t)(row0 + 3) * 192 + fi] = o3;
    }
}

// ---------------- mono fallback (R5 verified, 162us) ----------------
#define COMPRESS(B, ZCOUT)                                                 \
    {                                                                      \
        double da[8];                                                      \
        _Pragma("unroll") for (int d = 0; d < 8; ++d) da[d] = 0.0;         \
        _Pragma("unroll") for (int j = 0; j < 3; ++j) {                    \
            const float4 zv = (j == 0) ? B##0 : (j == 1) ? B##1 : B##2;    \
            const int fi = lane + 64 * j;                                  \
            const int sw = fi & 7;                                         \
            float f[8];                                                    \
            _Pragma("unroll") for (int d = 0; d < 8; ++d) f[d] = 0.f;      \
            _Pragma("unroll") for (int k = 0; k < 4; ++k) {                \
                const float a = (k==0)?zv.x:(k==1)?zv.y:(k==2)?zv.z:zv.w;  \
                const int a0 = 8 * fi + 2 * k;                             \
                const float4 wA = lds_w[a0 ^ sw];                          \
                const float4 wB = lds_w[(a0 + 1) ^ sw];                    \
                f[0]=fmaf(a,wA.x,f[0]); f[1]=fmaf(a,wA.y,f[1]);            \
                f[2]=fmaf(a,wA.z,f[2]); f[3]=fmaf(a,wA.w,f[3]);            \
                f[4]=fmaf(a,wB.x,f[4]); f[5]=fmaf(a,wB.y,f[5]);            \
                f[6]=fmaf(a,wB.z,f[6]); f[7]=fmaf(a,wB.w,f[7]);            \
            }                                                              \
            _Pragma("unroll") for (int d = 0; d < 8; ++d)                  \
                da[d] += (double)f[d];                                     \
        }                                                                  \
        REDUCE_TO_MINE(da, ZCOUT)                                         \
        ZCOUT += bc_mine;                                                  \
    }

#define FINISH(row, ZC, UVF)                                               \
    {                                                                      \
        const double uv = (double)(UVF) + 1e-10;                           \
        const double g  = -log(-log(uv));                                  \
        double n  = g - fabs(ZC - (double)cb_mine);                        \
        int    li = lev;                                                   \
        float  ci = cb_mine;                                               \
        _Pragma("unroll") for (int s = 8; s <= 32; s <<= 1) {              \
            const double on = __shfl_xor(n, s);                            \
            const int    ol = __shfl_xor(li, s);                           \
            const float  oc = __shfl_xor(ci, s);                           \
            const bool   t  = (on > n) || (on == n && ol < li);            \
            n = t ? on : n; li = t ? ol : li; ci = t ? oc : ci;            \
        }                                                                  \
        const double e = ZC - (double)ci;                                  \
        qa += e * e;                                                       \
        float code[8];                                                     \
        _Pragma("unroll") for (int d = 0; d < 8; ++d)                      \
            code[d] = __shfl(ci, (lane & 56) | d);                         \
        _Pragma("unroll") for (int j = 0; j < 3; ++j) {                    \
            const int fi = lane + 64 * j;                                  \
            float4 o = be4[fi];                                            \
            _Pragma("unroll") for (int d = 0; d < 8; ++d) {                \
                const float4 wv = We4[d * 192 + fi];                       \
                o.x = fmaf(code[d], wv.x, o.x);                            \
                o.y = fmaf(code[d], wv.y, o.y);                            \
                o.z = fmaf(code[d], wv.z, o.z);                            \
                o.w = fmaf(code[d], wv.w, o.w);                            \
            }                                                              \
            zq4[(size_t)(row) * 192 + fi] = o;                             \
        }                                                                  \
    }

__global__ __launch_bounds__(256) void fsq_mono(
    const float* __restrict__ z, const float* __restrict__ u,
    const float* __restrict__ Wc, const float* __restrict__ bc,
    const float* __restrict__ We, const float* __restrict__ be,
    const float* __restrict__ cb, float* __restrict__ zq,
    double* __restrict__ bpart)
{
    __shared__ float4 lds_w[1536];
    __shared__ double wsum[4];

    const int lane = threadIdx.x & 63;
    const int wid  = threadIdx.x >> 6;
    const int dg   = lane & 7;
    const int lev  = lane >> 3;

    {
        const float4* __restrict__ Wc4 = (const float4*)Wc;
        for (int t = threadIdx.x; t < 1536; t += 256)
            lds_w[t ^ ((t >> 3) & 7)] = Wc4[t];
    }

    const float  cb_mine = cb[dg * 8 + lev];
    const double bc_mine = (double)bc[dg];
    const int b0 = lane & 1, b1 = (lane >> 1) & 1, b2 = (lane >> 2) & 1;

    const float4* __restrict__ z4  = (const float4*)z;
    const float4* __restrict__ We4 = (const float4*)We;
    const float4* __restrict__ be4 = (const float4*)be;
    float4* __restrict__ zq4 = (float4*)zq;

    const int wbase = (blockIdx.x * 4 + wid) * RPW;
    double qa = 0.0;

    __syncthreads();

    float4 zA0, zA1, zA2, zB0, zB1, zB2;
    float  zAu, zBu;
    double zcA, zcB;
    LOADZ(zA, wbase)
#pragma unroll 1
    for (int itp = 0; itp < RPW / 2; ++itp) {
        const int r0 = wbase + 2 * itp;
        LOADZ(zB, r0 + 1)
        COMPRESS(zA, zcA)
        const float uvA = zAu;
        FINISH(r0, zcA, uvA)
        COMPRESS(zB, zcB)
        const float uvB = zBu;
        if (itp != RPW / 2 - 1) { LOADZ(zA, r0 + 2) }
        FINISH(r0 + 1, zcB, uvB)
    }

    qa += __shfl_xor(qa, 1);
    qa += __shfl_xor(qa, 2);
    qa += __shfl_xor(qa, 4);
    if (lane == 0) wsum[wid] = qa;
    __syncthreads();
    if (threadIdx.x == 0)
        bpart[blockIdx.x] = (wsum[0] + wsum[1]) + (wsum[2] + wsum[3]);
}

__global__ __launch_bounds__(256) void fsq_tail_bpart(
    const double* __restrict__ bpart, float* __restrict__ out)
{
    __shared__ double s[256];
    const int t = threadIdx.x;
    double a = 0.0;
    for (int i = 0; i < NBLK / 256; ++i)          // fixed order
        a += bpart[t * (NBLK / 256) + i];
    s[t] = a;
    __syncthreads();
    for (int w = 128; w > 0; w >>= 1) {
        if (t < w) s[t] += s[t + w];
        __syncthreads();
    }
    if (t == 0) out[0] = (float)(s[0] * (1.0 / QCOUNT));
}

extern "C" void kernel_launch(void* const* d_in, const int* in_sizes, int n_in,
                              void* d_out, int out_size, void* d_ws, size_t ws_size,
                              hipStream_t stream)
{
    const float* z  = (const float*)d_in[0];
    const float* u  = (const float*)d_in[1];
    const float* Wc = (const float*)d_in[2];
    const float* bc = (const float*)d_in[3];
    const float* We = (const float*)d_in[4];
    const float* be = (const float*)d_in[5];
    const float* cb = (const float*)d_in[6];
    // d_in[7] = codebook_mask: all levels == 8 -> mask all true, unused.

    float*  zq    = (float*)d_out;
    double* bpart = (double*)d_ws;

    const size_t bpart_bytes = (size_t)NBLK * sizeof(double);       // 32 KB
    const size_t codes_bytes = (size_t)NROWS * sizeof(unsigned);    // 256 KB

    if (ws_size >= bpart_bytes + codes_bytes) {
        unsigned* codes = (unsigned*)((char*)d_ws + bpart_bytes);
        fsq_code<<<dim3(NBLK), dim3(256), 0, stream>>>(z, u, Wc, bc, cb, codes, bpart);
        fsq_expand<<<dim3(NBLK2), dim3(256), 0, stream>>>(codes, We, be, cb, bpart, zq);
    } else {
        // fallback: R5 mono kernel
        fsq_mono<<<dim3(NBLK), dim3(256), 0, stream>>>(z, u, Wc, bc, We, be, cb, zq, bpart);
        fsq_tail_bpart<<<dim3(1), dim3(256), 0, stream>>>(bpart, zq + (size_t)NROWS * CIN);
    }
}

// Round 10
// 111.225 us; speedup vs baseline: 1.7813x; 1.3057x over previous
//
#include <hip/hip_runtime.h>
#include <math.h>

// Problem constants (match reference)
#define NROWS 65536          // B*S = 16*4096
#define CIN   768
#define QCOUNT 524288.0      // NROWS * DDIM
#define RPW   8              // rows per wave, pass 1 (4 pairs, ping-pong prefetch)
#define NBLK1 (NROWS / (4 * RPW))   // 2048 blocks of 4 waves (pass 1)
#define NBLK2 (NROWS / 16)          // 4096 blocks, expand: 4 rows/wave
#define RPW_M  4                    // mono fallback
#define NBLK_M (NROWS / (4 * RPW_M))

// R10: two-pass (R7/R9) + COMPRESS2 + restored depth-1 pair prefetch
// (R9 post-mortem: dropping it exposed ~900cy HBM latency per pair) +
// f32 fast-path gumbel with provably-safe f64 fallback (two serial f64
// logs/row were ~400cy of VALU chain; __logf pair ~20cy; rows where the
// f32 argmax margin < 1e-3 (~1-2%) redo exact f64 — bit-identical result).

// Distributing butterfly: reduce 8 per-lane f64 partials across 64 lanes,
// delivering zc[d] to lanes with (lane&7)==d. Fixed order, static selects.
#define REDUCE_TO_MINE(da, out)                                            \
    {                                                                      \
        double k0 = b0 ? da[1] : da[0], s0 = b0 ? da[0] : da[1];           \
        double k1 = b0 ? da[3] : da[2], s1 = b0 ? da[2] : da[3];           \
        double k2 = b0 ? da[5] : da[4], s2 = b0 ? da[4] : da[5];           \
        double k3 = b0 ? da[7] : da[6], s3 = b0 ? da[6] : da[7];           \
        k0 += __shfl_xor(s0, 1); k1 += __shfl_xor(s1, 1);                  \
        k2 += __shfl_xor(s2, 1); k3 += __shfl_xor(s3, 1);                  \
        double m0 = b1 ? k1 : k0, t0 = b1 ? k0 : k1;                       \
        double m1 = b1 ? k3 : k2, t1 = b1 ? k2 : k3;                       \
        m0 += __shfl_xor(t0, 2); m1 += __shfl_xor(t1, 2);                  \
        double r = b2 ? m1 : m0, tq = b2 ? m0 : m1;                        \
        r += __shfl_xor(tq, 4);                                            \
        r += __shfl_xor(r, 8);                                             \
        r += __shfl_xor(r, 16);                                            \
        r += __shfl_xor(r, 32);                                            \
        out = r;                                                           \
    }

// Load one row's z (3 coalesced float4) + u (coalesced permuted 256B)
#define LOADZ(B, row)                                                      \
    B##0 = z4[(size_t)(row) * 192 + lane];                                 \
    B##1 = z4[(size_t)(row) * 192 + lane + 64];                           \
    B##2 = z4[(size_t)(row) * 192 + lane + 128];                          \
    B##u = u[(size_t)(row) * 64 + dg * 8 + lev];

// compress TWO rows (buffers P,Q) sharing each Wc LDS read. Per-row
// arithmetic is the EXACT order of the verified absmax-0.0 kernel.
#define COMPRESS2(P, Q, ZCA, ZCB)                                          \
    {                                                                      \
        double da0[8], da1[8];                                             \
        _Pragma("unroll") for (int d = 0; d < 8; ++d) { da0[d]=0.0; da1[d]=0.0; } \
        _Pragma("unroll") for (int j = 0; j < 3; ++j) {                    \
            const float4 zvA = (j == 0) ? P##0 : (j == 1) ? P##1 : P##2;   \
            const float4 zvB = (j == 0) ? Q##0 : (j == 1) ? Q##1 : Q##2;   \
            const int fi = lane + 64 * j;                                  \
            const int sw = fi & 7;                                         \
            float fA[8], fB[8];                                            \
            _Pragma("unroll") for (int d = 0; d < 8; ++d) { fA[d]=0.f; fB[d]=0.f; } \
            _Pragma("unroll") for (int k = 0; k < 4; ++k) {                \
                const float aA = (k==0)?zvA.x:(k==1)?zvA.y:(k==2)?zvA.z:zvA.w; \
                const float aB = (k==0)?zvB.x:(k==1)?zvB.y:(k==2)?zvB.z:zvB.w; \
                const int a0 = 8 * fi + 2 * k;                             \
                const float4 wA = lds_w[a0 ^ sw];                          \
                const float4 wB = lds_w[(a0 + 1) ^ sw];                    \
                fA[0]=fmaf(aA,wA.x,fA[0]); fA[1]=fmaf(aA,wA.y,fA[1]);      \
                fA[2]=fmaf(aA,wA.z,fA[2]); fA[3]=fmaf(aA,wA.w,fA[3]);      \
                fA[4]=fmaf(aA,wB.x,fA[4]); fA[5]=fmaf(aA,wB.y,fA[5]);      \
                fA[6]=fmaf(aA,wB.z,fA[6]); fA[7]=fmaf(aA,wB.w,fA[7]);      \
                fB[0]=fmaf(aB,wA.x,fB[0]); fB[1]=fmaf(aB,wA.y,fB[1]);      \
                fB[2]=fmaf(aB,wA.z,fB[2]); fB[3]=fmaf(aB,wA.w,fB[3]);      \
                fB[4]=fmaf(aB,wB.x,fB[4]); fB[5]=fmaf(aB,wB.y,fB[5]);      \
                fB[6]=fmaf(aB,wB.z,fB[6]); fB[7]=fmaf(aB,wB.w,fB[7]);      \
            }                                                              \
            _Pragma("unroll") for (int d = 0; d < 8; ++d) {                \
                da0[d] += (double)fA[d];                                   \
                da1[d] += (double)fB[d];                                   \
            }                                                              \
        }                                                                  \
        REDUCE_TO_MINE(da0, ZCA)                                          \
        REDUCE_TO_MINE(da1, ZCB)                                          \
        ZCA += bc_mine;                                                    \
        ZCB += bc_mine;                                                    \
    }

// gumbel + argmax (f32 fast path, f64 fallback) + qerr + pack -> codes[row]
// Safety: winner provably identical to f64 when every loser trails by >1e-3
// (f32 gumbel abs error <= ~3e-6). Unsafe rows redo exact f64 (wave-uniform).
#define FIN_CODE(row, ZC, UVF)                                             \
    {                                                                      \
        const float  uvf = (UVF) + 1e-10f;                                 \
        const float  gf  = -__logf(-__logf(uvf));                          \
        const double dist = fabs(ZC - (double)cb_mine);                    \
        double n = (double)gf - dist;                                      \
        const double n_orig = n;                                           \
        int li = lev;                                                      \
        _Pragma("unroll") for (int s = 8; s <= 32; s <<= 1) {              \
            const double on = __shfl_xor(n, s);                            \
            const int    ol = __shfl_xor(li, s);                           \
            const bool   t  = (on > n) || (on == n && ol < li);            \
            n = t ? on : n; li = t ? ol : li;                              \
        }                                                                  \
        const bool safe = (li == lev) || (n - n_orig > 1e-3);              \
        if (!__all((int)safe)) {                                           \
            const double uv = (double)(UVF) + 1e-10;                       \
            n = -log(-log(uv)) - dist;   /* exact verified f64 path */     \
            li = lev;                                                      \
            _Pragma("unroll") for (int s = 8; s <= 32; s <<= 1) {          \
                const double on = __shfl_xor(n, s);                        \
                const int    ol = __shfl_xor(li, s);                       \
                const bool   t  = (on > n) || (on == n && ol < li);        \
                n = t ? on : n; li = t ? ol : li;                          \
            }                                                              \
        }                                                                  \
        const float ci = cbl[dg * 8 + li];   /* same f32 value as before */ \
        const double e = ZC - (double)ci;                                  \
        qa += e * e;                                                       \
        unsigned pk = (unsigned)li << (3 * dg);                            \
        pk += __shfl_xor(pk, 1);                                           \
        pk += __shfl_xor(pk, 2);                                           \
        pk += __shfl_xor(pk, 4);   /* full 24-bit pack in every lane */    \
        if (lane == 0) codes[row] = pk;                                    \
    }

// ---------------- Pass 1: compress + gumbel-argmax + qerr + codes ----------------
__global__ __launch_bounds__(256) void fsq_code(
    const float* __restrict__ z, const float* __restrict__ u,
    const float* __restrict__ Wc, const float* __restrict__ bc,
    const float* __restrict__ cb, unsigned* __restrict__ codes,
    double* __restrict__ bpart)
{
    __shared__ float4 lds_w[1536];   // Wc, XOR-swizzled
    __shared__ float  cbl[64];
    __shared__ double wsum[4];

    const int lane = threadIdx.x & 63;
    const int wid  = threadIdx.x >> 6;
    const int dg   = lane & 7;
    const int lev  = lane >> 3;

    {
        const float4* __restrict__ Wc4 = (const float4*)Wc;
        for (int t = threadIdx.x; t < 1536; t += 256)
            lds_w[t ^ ((t >> 3) & 7)] = Wc4[t];
        if (threadIdx.x < 64) cbl[threadIdx.x] = cb[threadIdx.x];
    }

    const float  cb_mine = cb[dg * 8 + lev];
    const double bc_mine = (double)bc[dg];
    const int b0 = lane & 1, b1 = (lane >> 1) & 1, b2 = (lane >> 2) & 1;

    const float4* __restrict__ z4 = (const float4*)z;

    const int wbase = (blockIdx.x * 4 + wid) * RPW;
    double qa = 0.0;

    __syncthreads();   // Wc image + cbl ready

    // ping-pong pair pipeline: load next pair before computing current pair
    float4 zA0, zA1, zA2, zB0, zB1, zB2, zC0, zC1, zC2, zD0, zD1, zD2;
    float  zAu, zBu, zCu, zDu;
    double zc0, zc1;

    LOADZ(zA, wbase + 0)
    LOADZ(zB, wbase + 1)
#pragma unroll 1
    for (int itp = 0; itp < RPW / 4; ++itp) {     // 2 iterations, 2 pairs each
        const int r0 = wbase + 4 * itp;
        LOADZ(zC, r0 + 2)                          // prefetch pair k+1
        LOADZ(zD, r0 + 3)
        COMPRESS2(zA, zB, zc0, zc1)
        FIN_CODE(r0, zc0, zAu)
        FIN_CODE(r0 + 1, zc1, zBu)
        if (itp != RPW / 4 - 1) {                  // prefetch pair k+2
            LOADZ(zA, r0 + 4)
            LOADZ(zB, r0 + 5)
        }
        COMPRESS2(zC, zD, zc0, zc1)
        FIN_CODE(r0 + 2, zc0, zCu)
        FIN_CODE(r0 + 3, zc1, zDu)
    }

    // qerr block partial (deterministic)
    qa += __shfl_xor(qa, 1);
    qa += __shfl_xor(qa, 2);
    qa += __shfl_xor(qa, 4);
    if (lane == 0) wsum[wid] = qa;
    __syncthreads();
    if (threadIdx.x == 0)
        bpart[blockIdx.x] = (wsum[0] + wsum[1]) + (wsum[2] + wsum[3]);
}

// ---------------- Pass 2: expand codes -> z_q (streaming, 4 rows/wave) ----
// Block 0 additionally performs the deterministic qerr tail reduction.
__global__ __launch_bounds__(256) void fsq_expand(
    const unsigned* __restrict__ codes, const float* __restrict__ We,
    const float* __restrict__ be, const float* __restrict__ cb,
    const double* __restrict__ bpart, float* __restrict__ zq)
{
    __shared__ float cbl[64];
    __shared__ double s[256];

    if (blockIdx.x == 0) {
        const int t = threadIdx.x;
        double a = 0.0;
        for (int i = 0; i < NBLK1 / 256; ++i)     // fixed order
            a += bpart[t * (NBLK1 / 256) + i];
        s[t] = a;
        __syncthreads();
        for (int w = 128; w > 0; w >>= 1) {
            if (t < w) s[t] += s[t + w];
            __syncthreads();
        }
        if (t == 0) zq[(size_t)NROWS * CIN] = (float)(s[0] * (1.0 / QCOUNT));
    }

    if (threadIdx.x < 64) cbl[threadIdx.x] = cb[threadIdx.x];
    __syncthreads();

    const int lane = threadIdx.x & 63;
    const int wid  = threadIdx.x >> 6;
    const int gw   = blockIdx.x * 4 + wid;
    const int row0 = gw * 4;

    const unsigned c0 = codes[row0];     // wave-uniform broadcast loads
    const unsigned c1 = codes[row0 + 1];
    const unsigned c2 = codes[row0 + 2];
    const unsigned c3 = codes[row0 + 3];

    float cd0[8], cd1[8], cd2[8], cd3[8];
#pragma unroll
    for (int d = 0; d < 8; ++d) {
        cd0[d] = cbl[d * 8 + ((c0 >> (3 * d)) & 7)];
        cd1[d] = cbl[d * 8 + ((c1 >> (3 * d)) & 7)];
        cd2[d] = cbl[d * 8 + ((c2 >> (3 * d)) & 7)];
        cd3[d] = cbl[d * 8 + ((c3 >> (3 * d)) & 7)];
    }

    const float4* __restrict__ We4 = (const float4*)We;
    const float4* __restrict__ be4 = (const float4*)be;
    float4* __restrict__ zq4 = (float4*)zq;
#pragma unroll
    for (int j = 0; j < 3; ++j) {
        const int fi = lane + 64 * j;
        const float4 bv = be4[fi];
        float4 o0 = bv, o1 = bv, o2 = bv, o3 = bv;
#pragma unroll
        for (int d = 0; d < 8; ++d) {
            const float4 wv = We4[d * 192 + fi];
            o0.x = fmaf(cd0[d], wv.x, o0.x); o0.y = fmaf(cd0[d], wv.y, o0.y);
            o0.z = fmaf(cd0[d], wv.z, o0.z); o0.w = fmaf(cd0[d], wv.w, o0.w);
            o1.x = fmaf(cd1[d], wv.x, o1.x); o1.y = fmaf(cd1[d], wv.y, o1.y);
            o1.z = fmaf(cd1[d], wv.z, o1.z); o1.w = fmaf(cd1[d], wv.w, o1.w);
            o2.x = fmaf(cd2[d], wv.x, o2.x); o2.y = fmaf(cd2[d], wv.y, o2.y);
            o2.z = fmaf(cd2[d], wv.z, o2.z); o2.w = fmaf(cd2[d], wv.w, o2.w);
            o3.x = fmaf(cd3[d], wv.x, o3.x); o3.y = fmaf(cd3[d], wv.y, o3.y);
            o3.z = fmaf(cd3[d], wv.z, o3.z); o3.w = fmaf(cd3[d], wv.w, o3.w);
        }
        zq4[(size_t)row0 * 192 + fi]       = o0;
        zq4[(size_t)(row0 + 1) * 192 + fi] = o1;
        zq4[(size_t)(row0 + 2) * 192 + fi] = o2;
        zq4[(size_t)(row0 + 3) * 192 + fi] = o3;
    }
}

// ---------------- mono fallback (R5 verified path, all-f64 logs) ----------------
#define COMPRESS_M(B, ZCOUT)                                               \
    {                                                                      \
        double da[8];                                                      \
        _Pragma("unroll") for (int d = 0; d < 8; ++d) da[d] = 0.0;         \
        _Pragma("unroll") for (int j = 0; j < 3; ++j) {                    \
            const float4 zv = (j == 0) ? B##0 : (j == 1) ? B##1 : B##2;    \
            const int fi = lane + 64 * j;                                  \
            const int sw = fi & 7;                                         \
            float f[8];                                                    \
            _Pragma("unroll") for (int d = 0; d < 8; ++d) f[d] = 0.f;      \
            _Pragma("unroll") for (int k = 0; k < 4; ++k) {                \
                const float a = (k==0)?zv.x:(k==1)?zv.y:(k==2)?zv.z:zv.w;  \
                const int a0 = 8 * fi + 2 * k;                             \
                const float4 wA = lds_w[a0 ^ sw];                          \
                const float4 wB = lds_w[(a0 + 1) ^ sw];                    \
                f[0]=fmaf(a,wA.x,f[0]); f[1]=fmaf(a,wA.y,f[1]);            \
                f[2]=fmaf(a,wA.z,f[2]); f[3]=fmaf(a,wA.w,f[3]);            \
                f[4]=fmaf(a,wB.x,f[4]); f[5]=fmaf(a,wB.y,f[5]);            \
                f[6]=fmaf(a,wB.z,f[6]); f[7]=fmaf(a,wB.w,f[7]);            \
            }                                                              \
            _Pragma("unroll") for (int d = 0; d < 8; ++d)                  \
                da[d] += (double)f[d];                                     \
        }                                                                  \
        REDUCE_TO_MINE(da, ZCOUT)                                         \
        ZCOUT += bc_mine;                                                  \
    }

#define FINISH_M(row, ZC, UVF)                                             \
    {                                                                      \
        const double uv = (double)(UVF) + 1e-10;                           \
        const double g  = -log(-log(uv));                                  \
        double n  = g - fabs(ZC - (double)cb_mine);                        \
        int    li = lev;                                                   \
        float  ci = cb_mine;                                               \
        _Pragma("unroll") for (int s = 8; s <= 32; s <<= 1) {              \
            const double on = __shfl_xor(n, s);                            \
            const int    ol = __shfl_xor(li, s);                           \
            const float  oc = __shfl_xor(ci, s);                           \
            const bool   t  = (on > n) || (on == n && ol < li);            \
            n = t ? on : n; li = t ? ol : li; ci = t ? oc : ci;            \
        }                                                                  \
        const double e = ZC - (double)ci;                                  \
        qa += e * e;                                                       \
        float code[8];                                                     \
        _Pragma("unroll") for (int d = 0; d < 8; ++d)                      \
            code[d] = __shfl(ci, (lane & 56) | d);                         \
        _Pragma("unroll") for (int j = 0; j < 3; ++j) {                    \
            const int fi = lane + 64 * j;                                  \
            float4 o = be4[fi];                                            \
            _Pragma("unroll") for (int d = 0; d < 8; ++d) {                \
                const float4 wv = We4[d * 192 + fi];                       \
                o.x = fmaf(code[d], wv.x, o.x);                            \
                o.y = fmaf(code[d], wv.y, o.y);                            \
                o.z = fmaf(code[d], wv.z, o.z);                            \
                o.w = fmaf(code[d], wv.w, o.w);                            \
            }                                                              \
            zq4[(size_t)(row) * 192 + fi] = o;                             \
        }                                                                  \
    }

__global__ __launch_bounds__(256) void fsq_mono(
    const float* __restrict__ z, const float* __restrict__ u,
    const float* __restrict__ Wc, const float* __restrict__ bc,
    const float* __restrict__ We, const float* __restrict__ be,
    const float* __restrict__ cb, float* __restrict__ zq,
    double* __restrict__ bpart)
{
    __shared__ float4 lds_w[1536];
    __shared__ double wsum[4];

    const int lane = threadIdx.x & 63;
    const int wid  = threadIdx.x >> 6;
    const int dg   = lane & 7;
    const int lev  = lane >> 3;

    {
        const float4* __restrict__ Wc4 = (const float4*)Wc;
        for (int t = threadIdx.x; t < 1536; t += 256)
            lds_w[t ^ ((t >> 3) & 7)] = Wc4[t];
    }

    const float  cb_mine = cb[dg * 8 + lev];
    const double bc_mine = (double)bc[dg];
    const int b0 = lane & 1, b1 = (lane >> 1) & 1, b2 = (lane >> 2) & 1;

    const float4* __restrict__ z4  = (const float4*)z;
    const float4* __restrict__ We4 = (const float4*)We;
    const float4* __restrict__ be4 = (const float4*)be;
    float4* __restrict__ zq4 = (float4*)zq;

    const int wbase = (blockIdx.x * 4 + wid) * RPW_M;
    double qa = 0.0;

    __syncthreads();

    float4 zA0, zA1, zA2, zB0, zB1, zB2;
    float  zAu, zBu;
    double zcA, zcB;
    LOADZ(zA, wbase)
#pragma unroll 1
    for (int itp = 0; itp < RPW_M / 2; ++itp) {
        const int r0 = wbase + 2 * itp;
        LOADZ(zB, r0 + 1)
        COMPRESS_M(zA, zcA)
        const float uvA = zAu;
        FINISH_M(r0, zcA, uvA)
        COMPRESS_M(zB, zcB)
        const float uvB = zBu;
        if (itp != RPW_M / 2 - 1) { LOADZ(zA, r0 + 2) }
        FINISH_M(r0 + 1, zcB, uvB)
    }

    qa += __shfl_xor(qa, 1);
    qa += __shfl_xor(qa, 2);
    qa += __shfl_xor(qa, 4);
    if (lane == 0) wsum[wid] = qa;
    __syncthreads();
    if (threadIdx.x == 0)
        bpart[blockIdx.x] = (wsum[0] + wsum[1]) + (wsum[2] + wsum[3]);
}

__global__ __launch_bounds__(256) void fsq_tail_bpart(
    const double* __restrict__ bpart, float* __restrict__ out)
{
    __shared__ double s[256];
    const int t = threadIdx.x;
    double a = 0.0;
    for (int i = 0; i < NBLK_M / 256; ++i)        // fixed order
        a += bpart[t * (NBLK_M / 256) + i];
    s[t] = a;
    __syncthreads();
    for (int w = 128; w > 0; w >>= 1) {
        if (t < w) s[t] += s[t + w];
        __syncthreads();
    }
    if (t == 0) out[0] = (float)(s[0] * (1.0 / QCOUNT));
}

extern "C" void kernel_launch(void* const* d_in, const int* in_sizes, int n_in,
                              void* d_out, int out_size, void* d_ws, size_t ws_size,
                              hipStream_t stream)
{
    const float* z  = (const float*)d_in[0];
    const float* u  = (const float*)d_in[1];
    const float* Wc = (const float*)d_in[2];
    const float* bc = (const float*)d_in[3];
    const float* We = (const float*)d_in[4];
    const float* be = (const float*)d_in[5];
    const float* cb = (const float*)d_in[6];
    // d_in[7] = codebook_mask: all levels == 8 -> mask all true, unused.

    float*  zq    = (float*)d_out;
    double* bpart = (double*)d_ws;

    const size_t bpart_bytes = (size_t)NBLK_M * sizeof(double);     // 32 KB (max of both paths)
    const size_t codes_bytes = (size_t)NROWS * sizeof(unsigned);    // 256 KB

    if (ws_size >= bpart_bytes + codes_bytes) {
        unsigned* codes = (unsigned*)((char*)d_ws + bpart_bytes);
        fsq_code<<<dim3(NBLK1), dim3(256), 0, stream>>>(z, u, Wc, bc, cb, codes, bpart);
        fsq_expand<<<dim3(NBLK2), dim3(256), 0, stream>>>(codes, We, be, cb, bpart, zq);
    } else {
        // fallback: R5-style mono kernel
        fsq_mono<<<dim3(NBLK_M), dim3(256), 0, stream>>>(z, u, Wc, bc, We, be, cb, zq, bpart);
        fsq_tail_bpart<<<dim3(1), dim3(256), 0, stream>>>(bpart, zq + (size_t)NROWS * CIN);
    }
}

// Round 11
// 101.466 us; speedup vs baseline: 1.9527x; 1.0962x over previous
//
#include <hip/hip_runtime.h>
#include <math.h>

// Problem constants (match reference)
#define NROWS 65536          // B*S = 16*4096
#define CIN   768
#define QCOUNT 524288.0      // NROWS * DDIM
#define RPW   8              // rows per wave (phase A: 4 pairs, ping-pong prefetch)
#define NBLK  (NROWS / (4 * RPW))   // 2048 blocks of 4 waves

// R11: fused phase kernel = R10's pass-1 (COMPRESS2 + fast-log + prefetch)
// + in-kernel expand phase (R8 revisited; its two regression causes —
// 4x bank conflicts from unshared COMPRESS, serial f64 logs — are fixed).
// Per wave: phase A codes 8 rows -> 8 packed u32 in LDS (no runtime-indexed
// regs); phase B expands them in two 4-row groups sharing We reads.
// Cross-wave, expand's HBM writes overlap other waves' DS/VALU compress.
// Decision path bit-identical to the verified absmax-0.0 kernels.

// Distributing butterfly: reduce 8 per-lane f64 partials across 64 lanes,
// delivering zc[d] to lanes with (lane&7)==d. Fixed order, static selects.
#define REDUCE_TO_MINE(da, out)                                            \
    {                                                                      \
        double k0 = b0 ? da[1] : da[0], s0 = b0 ? da[0] : da[1];           \
        double k1 = b0 ? da[3] : da[2], s1 = b0 ? da[2] : da[3];           \
        double k2 = b0 ? da[5] : da[4], s2 = b0 ? da[4] : da[5];           \
        double k3 = b0 ? da[7] : da[6], s3 = b0 ? da[6] : da[7];           \
        k0 += __shfl_xor(s0, 1); k1 += __shfl_xor(s1, 1);                  \
        k2 += __shfl_xor(s2, 1); k3 += __shfl_xor(s3, 1);                  \
        double m0 = b1 ? k1 : k0, t0 = b1 ? k0 : k1;                       \
        double m1 = b1 ? k3 : k2, t1 = b1 ? k2 : k3;                       \
        m0 += __shfl_xor(t0, 2); m1 += __shfl_xor(t1, 2);                  \
        double r = b2 ? m1 : m0, tq = b2 ? m0 : m1;                        \
        r += __shfl_xor(tq, 4);                                            \
        r += __shfl_xor(r, 8);                                             \
        r += __shfl_xor(r, 16);                                            \
        r += __shfl_xor(r, 32);                                            \
        out = r;                                                           \
    }

// Load one row's z (3 coalesced float4) + u (coalesced permuted 256B)
#define LOADZ(B, row)                                                      \
    B##0 = z4[(size_t)(row) * 192 + lane];                                 \
    B##1 = z4[(size_t)(row) * 192 + lane + 64];                           \
    B##2 = z4[(size_t)(row) * 192 + lane + 128];                          \
    B##u = u[(size_t)(row) * 64 + dg * 8 + lev];

// compress TWO rows (buffers P,Q) sharing each Wc LDS read. Per-row
// arithmetic is the EXACT order of the verified absmax-0.0 kernel.
#define COMPRESS2(P, Q, ZCA, ZCB)                                          \
    {                                                                      \
        double da0[8], da1[8];                                             \
        _Pragma("unroll") for (int d = 0; d < 8; ++d) { da0[d]=0.0; da1[d]=0.0; } \
        _Pragma("unroll") for (int j = 0; j < 3; ++j) {                    \
            const float4 zvA = (j == 0) ? P##0 : (j == 1) ? P##1 : P##2;   \
            const float4 zvB = (j == 0) ? Q##0 : (j == 1) ? Q##1 : Q##2;   \
            const int fi = lane + 64 * j;                                  \
            const int sw = fi & 7;                                         \
            float fA[8], fB[8];                                            \
            _Pragma("unroll") for (int d = 0; d < 8; ++d) { fA[d]=0.f; fB[d]=0.f; } \
            _Pragma("unroll") for (int k = 0; k < 4; ++k) {                \
                const float aA = (k==0)?zvA.x:(k==1)?zvA.y:(k==2)?zvA.z:zvA.w; \
                const float aB = (k==0)?zvB.x:(k==1)?zvB.y:(k==2)?zvB.z:zvB.w; \
                const int a0 = 8 * fi + 2 * k;                             \
                const float4 wA = lds_w[a0 ^ sw];                          \
                const float4 wB = lds_w[(a0 + 1) ^ sw];                    \
                fA[0]=fmaf(aA,wA.x,fA[0]); fA[1]=fmaf(aA,wA.y,fA[1]);      \
                fA[2]=fmaf(aA,wA.z,fA[2]); fA[3]=fmaf(aA,wA.w,fA[3]);      \
                fA[4]=fmaf(aA,wB.x,fA[4]); fA[5]=fmaf(aA,wB.y,fA[5]);      \
                fA[6]=fmaf(aA,wB.z,fA[6]); fA[7]=fmaf(aA,wB.w,fA[7]);      \
                fB[0]=fmaf(aB,wA.x,fB[0]); fB[1]=fmaf(aB,wA.y,fB[1]);      \
                fB[2]=fmaf(aB,wA.z,fB[2]); fB[3]=fmaf(aB,wA.w,fB[3]);      \
                fB[4]=fmaf(aB,wB.x,fB[4]); fB[5]=fmaf(aB,wB.y,fB[5]);      \
                fB[6]=fmaf(aB,wB.z,fB[6]); fB[7]=fmaf(aB,wB.w,fB[7]);      \
            }                                                              \
            _Pragma("unroll") for (int d = 0; d < 8; ++d) {                \
                da0[d] += (double)fA[d];                                   \
                da1[d] += (double)fB[d];                                   \
            }                                                              \
        }                                                                  \
        REDUCE_TO_MINE(da0, ZCA)                                          \
        REDUCE_TO_MINE(da1, ZCB)                                          \
        ZCA += bc_mine;                                                    \
        ZCB += bc_mine;                                                    \
    }

// gumbel + argmax (f32 fast path, provably-safe f64 fallback) + qerr +
// pack -> wcodes[wid*8 + slot] (LDS; avoids runtime-indexed registers).
#define FIN_CODE(slot, ZC, UVF)                                            \
    {                                                                      \
        const float  uvf = (UVF) + 1e-10f;                                 \
        const float  gf  = -__logf(-__logf(uvf));                          \
        const double dist = fabs(ZC - (double)cb_mine);                    \
        double n = (double)gf - dist;                                      \
        const double n_orig = n;                                           \
        int li = lev;                                                      \
        _Pragma("unroll") for (int s = 8; s <= 32; s <<= 1) {              \
            const double on = __shfl_xor(n, s);                            \
            const int    ol = __shfl_xor(li, s);                           \
            const bool   t  = (on > n) || (on == n && ol < li);            \
            n = t ? on : n; li = t ? ol : li;                              \
        }                                                                  \
        const bool safe = (li == lev) || (n - n_orig > 1e-3);              \
        if (!__all((int)safe)) {                                           \
            const double uv = (double)(UVF) + 1e-10;                       \
            n = -log(-log(uv)) - dist;   /* exact verified f64 path */     \
            li = lev;                                                      \
            _Pragma("unroll") for (int s = 8; s <= 32; s <<= 1) {          \
                const double on = __shfl_xor(n, s);                        \
                const int    ol = __shfl_xor(li, s);                       \
                const bool   t  = (on > n) || (on == n && ol < li);        \
                n = t ? on : n; li = t ? ol : li;                          \
            }                                                              \
        }                                                                  \
        const float ci = cbl[dg * 8 + li];   /* same f32 value as verified */ \
        const double e = ZC - (double)ci;                                  \
        qa += e * e;                                                       \
        unsigned pk = (unsigned)li << (3 * dg);                            \
        pk += __shfl_xor(pk, 1);                                           \
        pk += __shfl_xor(pk, 2);                                           \
        pk += __shfl_xor(pk, 4);   /* full 24-bit pack in every lane */    \
        if (lane == 0) wcodes[wid * 8 + (slot)] = pk;                      \
    }

template <int USE_BPART>
__global__ __launch_bounds__(256) void fsq_fused2(
    const float* __restrict__ z, const float* __restrict__ u,
    const float* __restrict__ Wc, const float* __restrict__ bc,
    const float* __restrict__ We, const float* __restrict__ be,
    const float* __restrict__ cb, float* __restrict__ zq,
    double* __restrict__ bpart)
{
    __shared__ float4   lds_w[1536];   // Wc, XOR-swizzled
    __shared__ float    cbl[64];
    __shared__ double   wsum[4];
    __shared__ unsigned wcodes[32];    // per-wave code parking (same-wave RW)

    const int lane = threadIdx.x & 63;
    const int wid  = threadIdx.x >> 6;
    const int dg   = lane & 7;
    const int lev  = lane >> 3;

    // ---- stage Wc (XOR-swizzled: idx ^ ((idx>>3)&7), involution) + cb ----
    {
        const float4* __restrict__ Wc4 = (const float4*)Wc;
        for (int t = threadIdx.x; t < 1536; t += 256)
            lds_w[t ^ ((t >> 3) & 7)] = Wc4[t];
        if (threadIdx.x < 64) cbl[threadIdx.x] = cb[threadIdx.x];
    }

    const float  cb_mine = cb[dg * 8 + lev];
    const double bc_mine = (double)bc[dg];
    const int b0 = lane & 1, b1 = (lane >> 1) & 1, b2 = (lane >> 2) & 1;

    const float4* __restrict__ z4 = (const float4*)z;

    const int wbase = (blockIdx.x * 4 + wid) * RPW;
    double qa = 0.0;

    __syncthreads();   // Wc image + cbl ready

    // ========== phase A: codes for all 8 rows (ping-pong pair pipeline) ==========
    float4 zA0, zA1, zA2, zB0, zB1, zB2, zC0, zC1, zC2, zD0, zD1, zD2;
    float  zAu, zBu, zCu, zDu;
    double zc0, zc1;

    LOADZ(zA, wbase + 0)
    LOADZ(zB, wbase + 1)
#pragma unroll 1
    for (int itp = 0; itp < RPW / 4; ++itp) {     // 2 iterations, 2 pairs each
        const int r0 = wbase + 4 * itp;
        const int s0 = 4 * itp;
        LOADZ(zC, r0 + 2)                          // prefetch pair k+1
        LOADZ(zD, r0 + 3)
        COMPRESS2(zA, zB, zc0, zc1)
        FIN_CODE(s0, zc0, zAu)
        FIN_CODE(s0 + 1, zc1, zBu)
        if (itp != RPW / 4 - 1) {                  // prefetch pair k+2
            LOADZ(zA, r0 + 4)
            LOADZ(zB, r0 + 5)
        }
        COMPRESS2(zC, zD, zc0, zc1)
        FIN_CODE(s0 + 2, zc0, zCu)
        FIN_CODE(s0 + 3, zc1, zDu)
    }

    // ========== phase B: expand the 8 rows, two 4-row groups ==========
    // (reads wcodes written by this same wave — compiler inserts lgkmcnt)
    {
        const float4* __restrict__ We4 = (const float4*)We;
        const float4* __restrict__ be4 = (const float4*)be;
        float4* __restrict__ zq4 = (float4*)zq;
#pragma unroll 1
        for (int g = 0; g < 2; ++g) {
            const int r0 = wbase + 4 * g;
            const unsigned c0 = wcodes[wid * 8 + 4 * g + 0];
            const unsigned c1 = wcodes[wid * 8 + 4 * g + 1];
            const unsigned c2 = wcodes[wid * 8 + 4 * g + 2];
            const unsigned c3 = wcodes[wid * 8 + 4 * g + 3];
            float cd0[8], cd1[8], cd2[8], cd3[8];
#pragma unroll
            for (int d = 0; d < 8; ++d) {
                cd0[d] = cbl[d * 8 + ((c0 >> (3 * d)) & 7)];
                cd1[d] = cbl[d * 8 + ((c1 >> (3 * d)) & 7)];
                cd2[d] = cbl[d * 8 + ((c2 >> (3 * d)) & 7)];
                cd3[d] = cbl[d * 8 + ((c3 >> (3 * d)) & 7)];
            }
#pragma unroll
            for (int j = 0; j < 3; ++j) {
                const int fi = lane + 64 * j;
                const float4 bv = be4[fi];
                float4 o0 = bv, o1 = bv, o2 = bv, o3 = bv;
#pragma unroll
                for (int d = 0; d < 8; ++d) {
                    const float4 wv = We4[d * 192 + fi];
                    o0.x = fmaf(cd0[d], wv.x, o0.x); o0.y = fmaf(cd0[d], wv.y, o0.y);
                    o0.z = fmaf(cd0[d], wv.z, o0.z); o0.w = fmaf(cd0[d], wv.w, o0.w);
                    o1.x = fmaf(cd1[d], wv.x, o1.x); o1.y = fmaf(cd1[d], wv.y, o1.y);
                    o1.z = fmaf(cd1[d], wv.z, o1.z); o1.w = fmaf(cd1[d], wv.w, o1.w);
                    o2.x = fmaf(cd2[d], wv.x, o2.x); o2.y = fmaf(cd2[d], wv.y, o2.y);
                    o2.z = fmaf(cd2[d], wv.z, o2.z); o2.w = fmaf(cd2[d], wv.w, o2.w);
                    o3.x = fmaf(cd3[d], wv.x, o3.x); o3.y = fmaf(cd3[d], wv.y, o3.y);
                    o3.z = fmaf(cd3[d], wv.z, o3.z); o3.w = fmaf(cd3[d], wv.w, o3.w);
                }
                zq4[(size_t)r0 * 192 + fi]       = o0;
                zq4[(size_t)(r0 + 1) * 192 + fi] = o1;
                zq4[(size_t)(r0 + 2) * 192 + fi] = o2;
                zq4[(size_t)(r0 + 3) * 192 + fi] = o3;
            }
        }
    }

    // ---- quantization error: dg-reduce once per wave ----
    qa += __shfl_xor(qa, 1);
    qa += __shfl_xor(qa, 2);
    qa += __shfl_xor(qa, 4);
    if (USE_BPART) {
        if (lane == 0) wsum[wid] = qa;
        __syncthreads();
        if (threadIdx.x == 0)
            bpart[blockIdx.x] = (wsum[0] + wsum[1]) + (wsum[2] + wsum[3]);
    } else {
        if (lane == 0) atomicAdd(bpart, qa);
    }
}

// Deterministic fixed-order reduction of NBLK partials -> mean -> out.
__global__ __launch_bounds__(256) void fsq_tail_bpart(
    const double* __restrict__ bpart, float* __restrict__ out)
{
    __shared__ double s[256];
    const int t = threadIdx.x;
    double a = 0.0;
    for (int i = 0; i < NBLK / 256; ++i)          // fixed order
        a += bpart[t * (NBLK / 256) + i];
    s[t] = a;
    __syncthreads();
    for (int w = 128; w > 0; w >>= 1) {
        if (t < w) s[t] += s[t + w];
        __syncthreads();
    }
    if (t == 0) out[0] = (float)(s[0] * (1.0 / QCOUNT));
}

__global__ void fsq_tail_atomic(const double* __restrict__ qacc, float* __restrict__ out)
{
    out[0] = (float)(qacc[0] * (1.0 / QCOUNT));
}

extern "C" void kernel_launch(void* const* d_in, const int* in_sizes, int n_in,
                              void* d_out, int out_size, void* d_ws, size_t ws_size,
                              hipStream_t stream)
{
    const float* z  = (const float*)d_in[0];
    const float* u  = (const float*)d_in[1];
    const float* Wc = (const float*)d_in[2];
    const float* bc = (const float*)d_in[3];
    const float* We = (const float*)d_in[4];
    const float* be = (const float*)d_in[5];
    const float* cb = (const float*)d_in[6];
    // d_in[7] = codebook_mask: all levels == 8 -> mask all true, unused.

    float*  zq    = (float*)d_out;
    double* bpart = (double*)d_ws;

    if (ws_size >= (size_t)NBLK * sizeof(double)) {
        // no memset needed: every block overwrites its own slot
        fsq_fused2<1><<<dim3(NBLK), dim3(256), 0, stream>>>(z, u, Wc, bc, We, be, cb, zq, bpart);
        fsq_tail_bpart<<<dim3(1), dim3(256), 0, stream>>>(bpart, zq + (size_t)NROWS * CIN);
    } else {
        hipMemsetAsync(d_ws, 0, sizeof(double), stream);
        fsq_fused2<0><<<dim3(NBLK), dim3(256), 0, stream>>>(z, u, Wc, bc, We, be, cb, zq, bpart);
        fsq_tail_atomic<<<dim3(1), dim3(1), 0, stream>>>(bpart, zq + (size_t)NROWS * CIN);
    }
}